// Round 1
// baseline (47.847 us; speedup 1.0000x reference)
//
#include <hip/hip_runtime.h>

// 3-level Haar (db1) DWT on [B=256, L=131072] float32.
// Each group of 8 consecutive input elements independently produces:
//   cA3[k], cD3[k], cD2[2k..2k+1], cD1[4k..4k+3]
// Output row layout: [cA3 (L/8), cD3 (L/8), cD2 (L/4), cD1 (L/2)].

#define INV_SQRT2 0.70710678118654752440f

__global__ void __launch_bounds__(256) dwt3_haar_kernel(
    const float* __restrict__ x, float* __restrict__ out) {
    const int L   = 131072;
    const int G   = L >> 3;          // 16384 groups of 8 per row
    const int gid = blockIdx.x * blockDim.x + threadIdx.x;  // < 256*16384 = 2^22

    const int row = gid >> 14;       // G = 2^14
    const int k   = gid & (G - 1);

    const int in_base = row * L + (k << 3);   // 32B-aligned
    const float4 a = *reinterpret_cast<const float4*>(x + in_base);
    const float4 b = *reinterpret_cast<const float4*>(x + in_base + 4);

    // Level 1
    const float cA1_0 = (a.x + a.y) * INV_SQRT2;
    const float cD1_0 = (a.x - a.y) * INV_SQRT2;
    const float cA1_1 = (a.z + a.w) * INV_SQRT2;
    const float cD1_1 = (a.z - a.w) * INV_SQRT2;
    const float cA1_2 = (b.x + b.y) * INV_SQRT2;
    const float cD1_2 = (b.x - b.y) * INV_SQRT2;
    const float cA1_3 = (b.z + b.w) * INV_SQRT2;
    const float cD1_3 = (b.z - b.w) * INV_SQRT2;

    // Level 2
    const float cA2_0 = (cA1_0 + cA1_1) * INV_SQRT2;
    const float cD2_0 = (cA1_0 - cA1_1) * INV_SQRT2;
    const float cA2_1 = (cA1_2 + cA1_3) * INV_SQRT2;
    const float cD2_1 = (cA1_2 - cA1_3) * INV_SQRT2;

    // Level 3
    const float cA3 = (cA2_0 + cA2_1) * INV_SQRT2;
    const float cD3 = (cA2_0 - cA2_1) * INV_SQRT2;

    const int row_out = row * L;
    out[row_out + k]            = cA3;                    // cA3 region @ 0
    out[row_out + (L >> 3) + k] = cD3;                    // cD3 region @ L/8

    float2 d2; d2.x = cD2_0; d2.y = cD2_1;                // cD2 region @ L/4
    *reinterpret_cast<float2*>(out + row_out + (L >> 2) + (k << 1)) = d2;

    float4 d1; d1.x = cD1_0; d1.y = cD1_1; d1.z = cD1_2; d1.w = cD1_3;
    *reinterpret_cast<float4*>(out + row_out + (L >> 1) + (k << 2)) = d1;  // cD1 @ L/2
}

extern "C" void kernel_launch(void* const* d_in, const int* in_sizes, int n_in,
                              void* d_out, int out_size, void* d_ws, size_t ws_size,
                              hipStream_t stream) {
    const float* x = (const float*)d_in[0];
    float* out = (float*)d_out;

    const int total_groups = (256 * 131072) / 8;   // 4,194,304 threads
    const int block = 256;
    const int grid = total_groups / block;         // 16384 blocks

    dwt3_haar_kernel<<<grid, block, 0, stream>>>(x, out);
}

// Round 3
// 47.433 us; speedup vs baseline: 1.0087x; 1.0087x over previous
//
#include <hip/hip_runtime.h>

// 3-level Haar (db1) DWT on [B=256, L=131072] float32.
// Each thread processes 16 consecutive input elements (2 groups of 8):
//   -> cA3 x2, cD3 x2, cD2 x4, cD1 x8
// Output row layout: [cA3 (L/8), cD3 (L/8), cD2 (L/4), cD1 (L/2)].
// All stores nontemporal (output never re-read on device); widths >= 8B/lane.
// Note: __builtin_nontemporal_store requires clang ext_vector types, not
// HIP_vector_type (float4) — hence f32x2/f32x4 below.

#define INV_SQRT2 0.70710678118654752440f

typedef float f32x2 __attribute__((ext_vector_type(2)));
typedef float f32x4 __attribute__((ext_vector_type(4)));

__global__ void __launch_bounds__(256) dwt3_haar_kernel16(
    const float* __restrict__ x, float* __restrict__ out) {
    const int L   = 131072;
    const int T   = L >> 4;          // 8192 chunks of 16 elems per row
    const int gid = blockIdx.x * blockDim.x + threadIdx.x;

    const int row = gid >> 13;       // T = 2^13
    const int t   = gid & (T - 1);   // chunk index within row

    const int in_base = row * L + (t << 4);   // 64B-aligned
    const f32x4 v0 = *reinterpret_cast<const f32x4*>(x + in_base);
    const f32x4 v1 = *reinterpret_cast<const f32x4*>(x + in_base + 4);
    const f32x4 v2 = *reinterpret_cast<const f32x4*>(x + in_base + 8);
    const f32x4 v3 = *reinterpret_cast<const f32x4*>(x + in_base + 12);

    // Level 1: 8 pairs
    const float cA1_0 = (v0.x + v0.y) * INV_SQRT2;
    const float cD1_0 = (v0.x - v0.y) * INV_SQRT2;
    const float cA1_1 = (v0.z + v0.w) * INV_SQRT2;
    const float cD1_1 = (v0.z - v0.w) * INV_SQRT2;
    const float cA1_2 = (v1.x + v1.y) * INV_SQRT2;
    const float cD1_2 = (v1.x - v1.y) * INV_SQRT2;
    const float cA1_3 = (v1.z + v1.w) * INV_SQRT2;
    const float cD1_3 = (v1.z - v1.w) * INV_SQRT2;
    const float cA1_4 = (v2.x + v2.y) * INV_SQRT2;
    const float cD1_4 = (v2.x - v2.y) * INV_SQRT2;
    const float cA1_5 = (v2.z + v2.w) * INV_SQRT2;
    const float cD1_5 = (v2.z - v2.w) * INV_SQRT2;
    const float cA1_6 = (v3.x + v3.y) * INV_SQRT2;
    const float cD1_6 = (v3.x - v3.y) * INV_SQRT2;
    const float cA1_7 = (v3.z + v3.w) * INV_SQRT2;
    const float cD1_7 = (v3.z - v3.w) * INV_SQRT2;

    // Level 2: 4 pairs
    const float cA2_0 = (cA1_0 + cA1_1) * INV_SQRT2;
    const float cD2_0 = (cA1_0 - cA1_1) * INV_SQRT2;
    const float cA2_1 = (cA1_2 + cA1_3) * INV_SQRT2;
    const float cD2_1 = (cA1_2 - cA1_3) * INV_SQRT2;
    const float cA2_2 = (cA1_4 + cA1_5) * INV_SQRT2;
    const float cD2_2 = (cA1_4 - cA1_5) * INV_SQRT2;
    const float cA2_3 = (cA1_6 + cA1_7) * INV_SQRT2;
    const float cD2_3 = (cA1_6 - cA1_7) * INV_SQRT2;

    // Level 3: 2 pairs
    const float cA3_0 = (cA2_0 + cA2_1) * INV_SQRT2;
    const float cD3_0 = (cA2_0 - cA2_1) * INV_SQRT2;
    const float cA3_1 = (cA2_2 + cA2_3) * INV_SQRT2;
    const float cD3_1 = (cA2_2 - cA2_3) * INV_SQRT2;

    const int row_out = row * L;

    f32x2 a3; a3.x = cA3_0; a3.y = cA3_1;
    __builtin_nontemporal_store(a3,
        reinterpret_cast<f32x2*>(out + row_out + (t << 1)));

    f32x2 d3; d3.x = cD3_0; d3.y = cD3_1;
    __builtin_nontemporal_store(d3,
        reinterpret_cast<f32x2*>(out + row_out + (L >> 3) + (t << 1)));

    f32x4 d2; d2.x = cD2_0; d2.y = cD2_1; d2.z = cD2_2; d2.w = cD2_3;
    __builtin_nontemporal_store(d2,
        reinterpret_cast<f32x4*>(out + row_out + (L >> 2) + (t << 2)));

    f32x4 d1a; d1a.x = cD1_0; d1a.y = cD1_1; d1a.z = cD1_2; d1a.w = cD1_3;
    f32x4 d1b; d1b.x = cD1_4; d1b.y = cD1_5; d1b.z = cD1_6; d1b.w = cD1_7;
    float* d1p = out + row_out + (L >> 1) + (t << 3);
    __builtin_nontemporal_store(d1a, reinterpret_cast<f32x4*>(d1p));
    __builtin_nontemporal_store(d1b, reinterpret_cast<f32x4*>(d1p + 4));
}

extern "C" void kernel_launch(void* const* d_in, const int* in_sizes, int n_in,
                              void* d_out, int out_size, void* d_ws, size_t ws_size,
                              hipStream_t stream) {
    const float* x = (const float*)d_in[0];
    float* out = (float*)d_out;

    const int total_threads = (256 * 131072) / 16;  // 2,097,152
    const int block = 256;
    const int grid = total_threads / block;         // 8192 blocks

    dwt3_haar_kernel16<<<grid, block, 0, stream>>>(x, out);
}